// Round 2
// baseline (840.386 us; speedup 1.0000x reference)
//
#include <hip/hip_runtime.h>
#include <stdint.h>

#define NB 2
#define CH 384
#define NH 8
#define CPH 48
#define IMG 128
#define HW 16384

typedef float f32x4 __attribute__((ext_vector_type(4)));
typedef short bf16x8 __attribute__((ext_vector_type(8)));
typedef short short4v __attribute__((ext_vector_type(4)));

__device__ inline unsigned short f2bf(float f){
    unsigned u = __builtin_bit_cast(unsigned, f);
    u += 0x7FFFu + ((u >> 16) & 1u);
    return (unsigned short)(u >> 16);
}
__device__ inline float bf2f(unsigned short h){
    unsigned u = ((unsigned)h) << 16;
    return __builtin_bit_cast(float, u);
}

// ===========================================================================
// NEW PATH
// ===========================================================================

// ---------------------------------------------------------------------------
// k_conv3: one block per (tensor, b, ch) plane. dwconv3x3.
//   tensor 0 (q), 1 (k): write hi/lo bf16 split + per-channel sum-of-squares
//   tensor 2 (v): write single bf16
// Block-per-plane => wave's load window is one 64KB plane (L1-resident).
// ---------------------------------------------------------------------------
__global__ __launch_bounds__(256) void k_conv3(
    const float* __restrict__ qf, const float* __restrict__ kf,
    const float* __restrict__ vf,
    const float* __restrict__ wq, const float* __restrict__ wk,
    const float* __restrict__ wv,
    unsigned short* __restrict__ Qh, unsigned short* __restrict__ Ql,
    unsigned short* __restrict__ Kh, unsigned short* __restrict__ Kl,
    unsigned short* __restrict__ Vc, float* __restrict__ ssqg)
{
    const int p = blockIdx.x;            // 0..2303
    const int tensor = p / 768;          // 0=q,1=k,2=v
    const int bc = p % 768;              // b*384+ch
    const int ch = bc % CH, b = bc / CH;

    const float* plane; const float* wp9;
    unsigned short *oh, *ol;
    if (tensor == 0) { plane = qf + (size_t)bc * HW; wp9 = wq + ch * 9;
                       oh = Qh + (size_t)bc * HW; ol = Ql + (size_t)bc * HW; }
    else if (tensor == 1) { plane = kf + (size_t)bc * HW; wp9 = wk + ch * 9;
                       oh = Kh + (size_t)bc * HW; ol = Kl + (size_t)bc * HW; }
    else             { plane = vf + (size_t)bc * HW; wp9 = wv + ch * 9;
                       oh = Vc + (size_t)bc * HW; ol = nullptr; }

    float w9[9];
#pragma unroll
    for (int i = 0; i < 9; ++i) w9[i] = wp9[i];

    const int t = threadIdx.x;
    const int y = t >> 1, x0 = (t & 1) * 64;
    unsigned short* ohp = oh + y * IMG;
    unsigned short* olp = ol ? ol + y * IMG : nullptr;

    float ssqacc = 0.f;
    float lft[3]; float4 c4[3];
    const float* rp[3]; bool rv[3];
#pragma unroll
    for (int dy = 0; dy < 3; ++dy) {
        int yy = y + dy - 1;
        rv[dy] = (yy >= 0 && yy < IMG);
        rp[dy] = plane + yy * IMG;
        lft[dy] = (rv[dy] && x0 > 0) ? rp[dy][x0 - 1] : 0.f;
        c4[dy] = rv[dy] ? *(const float4*)(rp[dy] + x0) : make_float4(0, 0, 0, 0);
    }
#pragma unroll
    for (int j = 0; j < 16; ++j) {
        const int xb = x0 + 4 * j;
        float4 n4[3];
#pragma unroll
        for (int dy = 0; dy < 3; ++dy) {
            if (j < 15)
                n4[dy] = rv[dy] ? *(const float4*)(rp[dy] + xb + 4) : make_float4(0, 0, 0, 0);
            else {
                float tl = (rv[dy] && (x0 + 64) < IMG) ? rp[dy][x0 + 64] : 0.f;
                n4[dy] = make_float4(tl, 0, 0, 0);
            }
        }
        float o0 = 0, o1 = 0, o2 = 0, o3 = 0;
#pragma unroll
        for (int dy = 0; dy < 3; ++dy) {
            float a0 = w9[dy * 3], a1 = w9[dy * 3 + 1], a2 = w9[dy * 3 + 2];
            o0 += a0 * lft[dy]  + a1 * c4[dy].x + a2 * c4[dy].y;
            o1 += a0 * c4[dy].x + a1 * c4[dy].y + a2 * c4[dy].z;
            o2 += a0 * c4[dy].y + a1 * c4[dy].z + a2 * c4[dy].w;
            o3 += a0 * c4[dy].z + a1 * c4[dy].w + a2 * n4[dy].x;
            lft[dy] = c4[dy].w; c4[dy] = n4[dy];
        }
        if (olp) {
            ssqacc += o0 * o0 + o1 * o1 + o2 * o2 + o3 * o3;
            unsigned short h0 = f2bf(o0), h1 = f2bf(o1), h2 = f2bf(o2), h3 = f2bf(o3);
            short4v hv = {(short)h0, (short)h1, (short)h2, (short)h3};
            short4v lv = {(short)f2bf(o0 - bf2f(h0)), (short)f2bf(o1 - bf2f(h1)),
                          (short)f2bf(o2 - bf2f(h2)), (short)f2bf(o3 - bf2f(h3))};
            *(short4v*)&ohp[xb] = hv;
            *(short4v*)&olp[xb] = lv;
        } else {
            short4v pv = {(short)f2bf(o0), (short)f2bf(o1), (short)f2bf(o2), (short)f2bf(o3)};
            *(short4v*)&ohp[xb] = pv;
        }
    }
    if (tensor < 2) {
        // block-reduce ssq, write (no atomics: block owns the whole plane)
#pragma unroll
        for (int off = 32; off; off >>= 1) ssqacc += __shfl_xor(ssqacc, off);
        __shared__ float ssr[4];
        const int lane = t & 63, wid = t >> 6;
        if (lane == 0) ssr[wid] = ssqacc;
        __syncthreads();
        if (t == 0) {
            int h = ch / CPH, c = ch % CPH;
            ssqg[(b * NH + h) * 96 + tensor * 48 + c] = ssr[0] + ssr[1] + ssr[2] + ssr[3];
        }
    }
}

// ---------------------------------------------------------------------------
// k_gram2: S[bh] = qh*(kh)^T + qh*(kl)^T + ql*(kh)^T over K=16384 (split)
// grid (32 ksplits, 16 bh), 4 waves; fragments loaded straight from global.
// ---------------------------------------------------------------------------
__global__ __launch_bounds__(256) void k_gram2(
    const unsigned short* __restrict__ Qh, const unsigned short* __restrict__ Ql,
    const unsigned short* __restrict__ Kh, const unsigned short* __restrict__ Kl,
    float* __restrict__ Sg)
{
    __shared__ float sred[4][2304];
    const int t = threadIdx.x;
    const int s = blockIdx.x, bh = blockIdx.y;
    const int wid = t >> 6, lane = t & 63, quad = lane >> 4, l15 = lane & 15;
    const size_t pbase = (size_t)((bh >> 3) * CH + (bh & 7) * CPH) * HW;

    f32x4 acc[3][3];
#pragma unroll
    for (int i = 0; i < 3; ++i)
#pragma unroll
        for (int j = 0; j < 3; ++j) acc[i][j] = (f32x4){0.f, 0.f, 0.f, 0.f};

    const int k0 = s * 512 + wid * 128;
#pragma unroll
    for (int ks = 0; ks < 4; ++ks) {
        const int px = k0 + ks * 32 + quad * 8;
        bf16x8 qh[3], ql_[3], kh[3], kl[3];
#pragma unroll
        for (int i = 0; i < 3; ++i) {
            size_t off = pbase + (size_t)(i * 16 + l15) * HW + px;
            qh[i]  = *(const bf16x8*)(Qh + off);
            ql_[i] = *(const bf16x8*)(Ql + off);
            kh[i]  = *(const bf16x8*)(Kh + off);
            kl[i]  = *(const bf16x8*)(Kl + off);
        }
#pragma unroll
        for (int ci = 0; ci < 3; ++ci)
#pragma unroll
            for (int di = 0; di < 3; ++di) {
                acc[ci][di] = __builtin_amdgcn_mfma_f32_16x16x32_bf16(qh[ci],  kh[di], acc[ci][di], 0, 0, 0);
                acc[ci][di] = __builtin_amdgcn_mfma_f32_16x16x32_bf16(qh[ci],  kl[di], acc[ci][di], 0, 0, 0);
                acc[ci][di] = __builtin_amdgcn_mfma_f32_16x16x32_bf16(ql_[ci], kh[di], acc[ci][di], 0, 0, 0);
            }
    }
#pragma unroll
    for (int ci = 0; ci < 3; ++ci)
#pragma unroll
        for (int di = 0; di < 3; ++di)
#pragma unroll
            for (int r = 0; r < 4; ++r)
                sred[wid][(ci * 16 + quad * 4 + r) * 48 + di * 16 + l15] = acc[ci][di][r];
    __syncthreads();
    float* Sbh = Sg + (size_t)bh * 2304;
#pragma unroll
    for (int i = 0; i < 9; ++i) {
        int e = t * 9 + i;
        atomicAdd(&Sbh[e], sred[0][e] + sred[1][e] + sred[2][e] + sred[3][e]);
    }
}

// ---------------------------------------------------------------------------
// k_attn: per attn row: normalize, rank, 4 nested-topk softmaxes -> M
// ---------------------------------------------------------------------------
__global__ void k_attn(const float* __restrict__ Sg, const float* __restrict__ ssqg,
                       const float* __restrict__ temp, const float* __restrict__ aw,
                       float* __restrict__ Mg)
{
    const int t = threadIdx.x;
    const int r = blockIdx.x * 4 + (t >> 6);
    const int lane = t & 63;
    const int c = r % 48, h = (r / 48) % NH, b = r / (48 * NH);
    const float* Srow = Sg + ((size_t)(b * NH + h) * 48 + c) * 48;
    const float* sq = ssqg + (size_t)(b * NH + h) * 96;

    float v = -3.0e38f;
    if (lane < 48) {
        float nq = fmaxf(sqrtf(sq[c]), 1e-12f);
        float nk = fmaxf(sqrtf(sq[48 + lane]), 1e-12f);
        v = Srow[lane] / (nq * nk) * temp[h];
    }
    float m = v;
#pragma unroll
    for (int off = 32; off; off >>= 1) m = fmaxf(m, __shfl_xor(m, off));
    int rank = 0;
    for (int e = 0; e < 48; ++e) {
        float ve = __shfl(v, e);
        rank += ((ve > v) || (ve == v && e < lane)) ? 1 : 0;
    }
    float ed = (lane < 48) ? __expf(v - m) : 0.f;
    const int K4[4] = {24, 32, 36, 38};
    float f = 0.f;
#pragma unroll
    for (int i = 0; i < 4; ++i) {
        float x = (rank < K4[i]) ? ed : 0.f;
#pragma unroll
        for (int off = 32; off; off >>= 1) x += __shfl_xor(x, off);
        if (rank < K4[i]) f += aw[i] / x;
    }
    if (lane < 48) Mg[((size_t)(b * NH + h) * 48 + c) * 48 + lane] = ed * f;
}

// ---------------------------------------------------------------------------
// k_w2: W2[b][co][gd] = sum_c Wproj[co][h*48+c] * M[b,h][c][d]  -> bf16
// ---------------------------------------------------------------------------
__global__ void k_w2(const float* __restrict__ wproj, const float* __restrict__ Mg,
                     unsigned short* __restrict__ W2)
{
    int idx = blockIdx.x * 256 + threadIdx.x;
    int gd = idx % 384; int co = (idx / 384) % 384; int b = idx / (384 * 384);
    int h = gd / 48, d = gd % 48;
    const float* wp = wproj + (size_t)co * 384 + h * 48;
    const float* Mp = Mg + (size_t)(b * NH + h) * 2304 + d;
    float s = 0.f;
#pragma unroll
    for (int cc = 0; cc < 48; ++cc) s += wp[cc] * Mp[cc * 48];
    W2[idx] = f2bf(s);
}

// ---------------------------------------------------------------------------
// k_trans: Vc[b][ch][n] -> Vct[b][n][ch]  (64x64 LDS tiles)
// ---------------------------------------------------------------------------
__global__ __launch_bounds__(256) void k_trans(const unsigned short* __restrict__ Vc,
                                               unsigned short* __restrict__ Vct)
{
    __shared__ unsigned short S[64][66];
    const int nt = blockIdx.x, ct = blockIdx.y, b = blockIdx.z;
    const int t = threadIdx.x, r = t >> 2, seg = t & 3;
    const unsigned short* src = Vc + (size_t)(b * CH + ct * 64 + r) * HW + nt * 64 + seg * 16;
    *(bf16x8*)&S[r][seg * 16]     = *(const bf16x8*)src;
    *(bf16x8*)&S[r][seg * 16 + 8] = *(const bf16x8*)(src + 8);
    __syncthreads();
    unsigned short tmp[16];
#pragma unroll
    for (int i = 0; i < 16; ++i) tmp[i] = S[seg * 16 + i][r];
    unsigned short* dst = Vct + ((size_t)b * HW + nt * 64 + r) * CH + ct * 64 + seg * 16;
    *(bf16x8*)dst       = *(const bf16x8*)&tmp[0];
    *(bf16x8*)(dst + 8) = *(const bf16x8*)&tmp[8];
}

// ---------------------------------------------------------------------------
// k_gemm2: out[b] = W2[b] (384x384) @ Vc[b] (384x16384), LDS-free MFMA GEMM.
// A (W2[co][k]) and B (Vct[n][k]) fragments are contiguous 16B global loads.
// grid (128 y, 3 mt, 2 b), 4 waves of 64co x 64pix.
// ---------------------------------------------------------------------------
__global__ __launch_bounds__(256) void k_gemm2(const unsigned short* __restrict__ W2,
        const unsigned short* __restrict__ Vct, float* __restrict__ out)
{
    const int t = threadIdx.x;
    const int y = blockIdx.x, mt = blockIdx.y, b = blockIdx.z;
    const int wid = t >> 6, lane = t & 63, quad = lane >> 4, l15 = lane & 15;
    const int wm = wid >> 1, wn = wid & 1;

    f32x4 acc[4][4];
#pragma unroll
    for (int i = 0; i < 4; ++i)
#pragma unroll
        for (int j = 0; j < 4; ++j) acc[i][j] = (f32x4){0.f, 0.f, 0.f, 0.f};

    const unsigned short* Ab[4];
    const unsigned short* Bb[4];
#pragma unroll
    for (int i = 0; i < 4; ++i) {
        Ab[i] = W2 + (size_t)(b * CH + mt * 128 + wm * 64 + i * 16 + l15) * CH + quad * 8;
        Bb[i] = Vct + ((size_t)b * HW + y * IMG + wn * 64 + i * 16 + l15) * CH + quad * 8;
    }

    for (int kt = 0; kt < 12; ++kt) {
        const int K0 = kt * 32;
        bf16x8 af[4], bfr[4];
#pragma unroll
        for (int i = 0; i < 4; ++i) af[i]  = *(const bf16x8*)(Ab[i] + K0);
#pragma unroll
        for (int i = 0; i < 4; ++i) bfr[i] = *(const bf16x8*)(Bb[i] + K0);
#pragma unroll
        for (int mi = 0; mi < 4; ++mi)
#pragma unroll
            for (int ni = 0; ni < 4; ++ni)
                acc[mi][ni] = __builtin_amdgcn_mfma_f32_16x16x32_bf16(af[mi], bfr[ni], acc[mi][ni], 0, 0, 0);
    }
#pragma unroll
    for (int mi = 0; mi < 4; ++mi)
#pragma unroll
        for (int ni = 0; ni < 4; ++ni)
#pragma unroll
            for (int r = 0; r < 4; ++r) {
                int co = mt * 128 + wm * 64 + mi * 16 + quad * 4 + r;
                int n  = y * IMG + wn * 64 + ni * 16 + l15;
                out[(size_t)(b * CH + co) * HW + n] = acc[mi][ni][r];
            }
}

// ===========================================================================
// OLD PATH (fallback if ws too small)
// ===========================================================================
__global__ __launch_bounds__(256, 2) void k_gram(
    const float* __restrict__ qf, const float* __restrict__ kf,
    const float* __restrict__ wq, const float* __restrict__ wk,
    float* __restrict__ Sg, float* __restrict__ ssqg)
{
    __shared__ union {
        unsigned short tiles[4][CPH][136];
        float sred[4 * CPH * CPH];
    } sm;
    const int t = threadIdx.x;
    const int band = blockIdx.x, h = blockIdx.y, b = blockIdx.z;
    const int y0 = band * 4;
    const int wid = t >> 6, lane = t & 63, quad = lane >> 4, l15 = lane & 15;
    const int px0 = wid * 32;
    const int slot = t % 96;
    const int half = t / 96;
    const int qk = slot / 48, c = slot % 48;
    const int x0 = half * 64;
    const float* plane = nullptr;
    float w9[9];
    if (t < 192) {
        int gc = h * CPH + c;
        plane = (qk == 0 ? qf : kf) + (size_t)(b * CH + gc) * HW;
        const float* wp = (qk == 0 ? wq : wk) + gc * 9;
#pragma unroll
        for (int i = 0; i < 9; ++i) w9[i] = wp[i];
    }
    float ssqacc = 0.f;
    f32x4 acc[3][3];
#pragma unroll
    for (int i = 0; i < 3; ++i)
#pragma unroll
        for (int j = 0; j < 3; ++j) acc[i][j] = (f32x4){0.f, 0.f, 0.f, 0.f};
    for (int yi = 0; yi < 4; ++yi) {
        const int y = y0 + yi;
        if (t < 192) {
            float lft[3]; float4 c4[3];
            const float* rp[3]; bool rv[3];
#pragma unroll
            for (int dy = 0; dy < 3; ++dy) {
                int yy = y + dy - 1;
                rv[dy] = (yy >= 0 && yy < IMG);
                rp[dy] = plane + yy * IMG;
                lft[dy] = (rv[dy] && x0 > 0) ? rp[dy][x0 - 1] : 0.f;
                c4[dy] = rv[dy] ? *(const float4*)(rp[dy] + x0) : make_float4(0, 0, 0, 0);
            }
#pragma unroll
            for (int j = 0; j < 16; ++j) {
                const int xb = x0 + 4 * j;
                float4 n4[3];
#pragma unroll
                for (int dy = 0; dy < 3; ++dy) {
                    if (j < 15)
                        n4[dy] = rv[dy] ? *(const float4*)(rp[dy] + xb + 4) : make_float4(0, 0, 0, 0);
                    else {
                        float tl = (rv[dy] && (x0 + 64) < IMG) ? rp[dy][x0 + 64] : 0.f;
                        n4[dy] = make_float4(tl, 0, 0, 0);
                    }
                }
                float o0 = 0, o1 = 0, o2 = 0, o3 = 0;
#pragma unroll
                for (int dy = 0; dy < 3; ++dy) {
                    float a0 = w9[dy * 3], a1 = w9[dy * 3 + 1], a2 = w9[dy * 3 + 2];
                    o0 += a0 * lft[dy]  + a1 * c4[dy].x + a2 * c4[dy].y;
                    o1 += a0 * c4[dy].x + a1 * c4[dy].y + a2 * c4[dy].z;
                    o2 += a0 * c4[dy].y + a1 * c4[dy].z + a2 * c4[dy].w;
                    o3 += a0 * c4[dy].z + a1 * c4[dy].w + a2 * n4[dy].x;
                    lft[dy] = c4[dy].w; c4[dy] = n4[dy];
                }
                ssqacc += o0 * o0 + o1 * o1 + o2 * o2 + o3 * o3;
                unsigned short hb0 = f2bf(o0), hb1 = f2bf(o1), hb2 = f2bf(o2), hb3 = f2bf(o3);
                short4v hv = {(short)hb0, (short)hb1, (short)hb2, (short)hb3};
                short4v lv = {(short)f2bf(o0 - bf2f(hb0)), (short)f2bf(o1 - bf2f(hb1)),
                              (short)f2bf(o2 - bf2f(hb2)), (short)f2bf(o3 - bf2f(hb3))};
                *(short4v*)&sm.tiles[qk * 2][c][xb] = hv;
                *(short4v*)&sm.tiles[qk * 2 + 1][c][xb] = lv;
            }
        }
        __syncthreads();
        bf16x8 qh[3], ql_[3], kh[3], kl[3];
#pragma unroll
        for (int i = 0; i < 3; ++i) {
            qh[i]  = *(const bf16x8*)&sm.tiles[0][i * 16 + l15][px0 + quad * 8];
            ql_[i] = *(const bf16x8*)&sm.tiles[1][i * 16 + l15][px0 + quad * 8];
            kh[i]  = *(const bf16x8*)&sm.tiles[2][i * 16 + l15][px0 + quad * 8];
            kl[i]  = *(const bf16x8*)&sm.tiles[3][i * 16 + l15][px0 + quad * 8];
        }
#pragma unroll
        for (int ci = 0; ci < 3; ++ci)
#pragma unroll
            for (int di = 0; di < 3; ++di) {
                acc[ci][di] = __builtin_amdgcn_mfma_f32_16x16x32_bf16(qh[ci],  kh[di], acc[ci][di], 0, 0, 0);
                acc[ci][di] = __builtin_amdgcn_mfma_f32_16x16x32_bf16(qh[ci],  kl[di], acc[ci][di], 0, 0, 0);
                acc[ci][di] = __builtin_amdgcn_mfma_f32_16x16x32_bf16(ql_[ci], kh[di], acc[ci][di], 0, 0, 0);
            }
        __syncthreads();
    }
#pragma unroll
    for (int ci = 0; ci < 3; ++ci)
#pragma unroll
        for (int di = 0; di < 3; ++di)
#pragma unroll
            for (int r = 0; r < 4; ++r) {
                int cc = ci * 16 + quad * 4 + r;
                int dd = di * 16 + l15;
                sm.sred[wid * 2304 + cc * 48 + dd] = acc[ci][di][r];
            }
    __syncthreads();
    {
        float* Sbh = Sg + (size_t)(b * NH + h) * 2304;
#pragma unroll
        for (int i = 0; i < 9; ++i) {
            int e = t * 9 + i;
            float s = sm.sred[e] + sm.sred[2304 + e] + sm.sred[4608 + e] + sm.sred[6912 + e];
            atomicAdd(&Sbh[e], s);
        }
    }
    if (t < 192) atomicAdd(&ssqg[((b * NH + h) * 2 + qk) * 48 + c], ssqacc);
}

__global__ __launch_bounds__(256) void k_vconv(const float* __restrict__ vf,
                                               const float* __restrict__ wv,
                                               unsigned short* __restrict__ Vc)
{
    const int bc = blockIdx.x;
    const int ch = bc % CH;
    const float* plane = vf + (size_t)bc * HW;
    const float* wp = wv + ch * 9;
    float w9[9];
#pragma unroll
    for (int i = 0; i < 9; ++i) w9[i] = wp[i];
    const int t = threadIdx.x;
    const int y = t >> 1, x0 = (t & 1) * 64;
    unsigned short* op = Vc + (size_t)bc * HW + y * IMG;
    float lft[3]; float4 c4[3];
    const float* rp[3]; bool rv[3];
#pragma unroll
    for (int dy = 0; dy < 3; ++dy) {
        int yy = y + dy - 1;
        rv[dy] = (yy >= 0 && yy < IMG);
        rp[dy] = plane + yy * IMG;
        lft[dy] = (rv[dy] && x0 > 0) ? rp[dy][x0 - 1] : 0.f;
        c4[dy] = rv[dy] ? *(const float4*)(rp[dy] + x0) : make_float4(0, 0, 0, 0);
    }
#pragma unroll
    for (int j = 0; j < 16; ++j) {
        const int xb = x0 + 4 * j;
        float4 n4[3];
#pragma unroll
        for (int dy = 0; dy < 3; ++dy) {
            if (j < 15)
                n4[dy] = rv[dy] ? *(const float4*)(rp[dy] + xb + 4) : make_float4(0, 0, 0, 0);
            else {
                float tl = (rv[dy] && (x0 + 64) < IMG) ? rp[dy][x0 + 64] : 0.f;
                n4[dy] = make_float4(tl, 0, 0, 0);
            }
        }
        float o0 = 0, o1 = 0, o2 = 0, o3 = 0;
#pragma unroll
        for (int dy = 0; dy < 3; ++dy) {
            float a0 = w9[dy * 3], a1 = w9[dy * 3 + 1], a2 = w9[dy * 3 + 2];
            o0 += a0 * lft[dy]  + a1 * c4[dy].x + a2 * c4[dy].y;
            o1 += a0 * c4[dy].x + a1 * c4[dy].y + a2 * c4[dy].z;
            o2 += a0 * c4[dy].y + a1 * c4[dy].z + a2 * c4[dy].w;
            o3 += a0 * c4[dy].z + a1 * c4[dy].w + a2 * n4[dy].x;
            lft[dy] = c4[dy].w; c4[dy] = n4[dy];
        }
        short4v pv = {(short)f2bf(o0), (short)f2bf(o1), (short)f2bf(o2), (short)f2bf(o3)};
        *(short4v*)&op[xb] = pv;
    }
}

__global__ __launch_bounds__(256) void k_gemm(const unsigned short* __restrict__ W2,
        const unsigned short* __restrict__ Vc,
        const float* __restrict__ vf, const float* __restrict__ wv,
        float* __restrict__ out, int staged)
{
    __shared__ unsigned short Ab[128][40];
    __shared__ unsigned short Bb[128][40];
    const int t = threadIdx.x;
    const int y = blockIdx.x, mt = blockIdx.y, b = blockIdx.z;
    const int wid = t >> 6, lane = t & 63, quad = lane >> 4, l15 = lane & 15;
    const int wm = wid >> 1, wn = wid & 1;
    f32x4 acc[4][4];
#pragma unroll
    for (int i = 0; i < 4; ++i)
#pragma unroll
        for (int j = 0; j < 4; ++j) acc[i][j] = (f32x4){0.f, 0.f, 0.f, 0.f};
    for (int kt = 0; kt < 12; ++kt) {
        const int K0 = kt * 32;
#pragma unroll
        for (int j = 0; j < 2; ++j) {
            int cid = t + 256 * j; int row = cid >> 2, k8 = cid & 3;
            bf16x8 vv = *(const bf16x8*)(W2 + ((size_t)(b * CH + mt * 128 + row) * CH + K0 + k8 * 8));
            *(bf16x8*)&Ab[row][k8 * 8] = vv;
        }
        if (staged) {
#pragma unroll
            for (int j = 0; j < 2; ++j) {
                int cid = t + 256 * j; int k = cid >> 4, x8 = cid & 15;
                bf16x8 vv = *(const bf16x8*)(Vc + ((size_t)(b * CH + K0 + k) * HW + y * IMG + x8 * 8));
#pragma unroll
                for (int i = 0; i < 8; ++i) Bb[x8 * 8 + i][k] = (unsigned short)vv[i];
            }
        } else {
            for (int j = 0; j < 2; ++j) {
                int cid = t + 256 * j; int k = cid >> 4, x8 = cid & 15;
                int gc = K0 + k;
                const float* plane = vf + (size_t)(b * CH + gc) * HW;
                const float* wp = wv + gc * 9;
                for (int i = 0; i < 8; ++i) {
                    int x = x8 * 8 + i; float s = 0.f;
                    for (int ky = 0; ky < 3; ++ky) {
                        int yy = y + ky - 1; if (yy < 0 || yy >= IMG) continue;
                        const float* rp = plane + yy * IMG;
                        for (int kx = 0; kx < 3; ++kx) {
                            int xx = x + kx - 1; if (xx < 0 || xx >= IMG) continue;
                            s += rp[xx] * wp[ky * 3 + kx];
                        }
                    }
                    Bb[x][k] = f2bf(s);
                }
            }
        }
        __syncthreads();
        bf16x8 af[4], bfr[4];
#pragma unroll
        for (int i = 0; i < 4; ++i) af[i]  = *(const bf16x8*)&Ab[wm * 64 + i * 16 + l15][quad * 8];
#pragma unroll
        for (int i = 0; i < 4; ++i) bfr[i] = *(const bf16x8*)&Bb[wn * 64 + i * 16 + l15][quad * 8];
#pragma unroll
        for (int mi = 0; mi < 4; ++mi)
#pragma unroll
            for (int ni = 0; ni < 4; ++ni)
                acc[mi][ni] = __builtin_amdgcn_mfma_f32_16x16x32_bf16(af[mi], bfr[ni], acc[mi][ni], 0, 0, 0);
        __syncthreads();
    }
#pragma unroll
    for (int mi = 0; mi < 4; ++mi)
#pragma unroll
        for (int ni = 0; ni < 4; ++ni)
#pragma unroll
            for (int r = 0; r < 4; ++r) {
                int co = mt * 128 + wm * 64 + mi * 16 + quad * 4 + r;
                int n  = y * IMG + wn * 64 + ni * 16 + l15;
                out[(size_t)(b * CH + co) * HW + n] = acc[mi][ni][r];
            }
}

// ---------------------------------------------------------------------------
extern "C" void kernel_launch(void* const* d_in, const int* in_sizes, int n_in,
                              void* d_out, int out_size, void* d_ws, size_t ws_size,
                              hipStream_t stream)
{
    const float* k_fea = (const float*)d_in[0];
    const float* v_fea = (const float*)d_in[1];
    const float* q_fea = (const float*)d_in[2];
    const float* wq = (const float*)d_in[3];
    const float* wk = (const float*)d_in[4];
    const float* wv = (const float*)d_in[5];
    const float* wproj = (const float*)d_in[6];
    const float* temp = (const float*)d_in[7];
    const float* aw = (const float*)d_in[8];
    float* out = (float*)d_out;

    char* ws = (char*)d_ws;
    // common small buffers
    float* Sg   = (float*)ws;                              // 147456 B
    float* ssqg = (float*)(ws + 147456);                   // 6144 B
    float* Mg   = (float*)(ws + 153600);                   // 147456 B
    unsigned short* W2 = (unsigned short*)(ws + 301056);   // 589824 B

    const size_t PLANE_BYTES = (size_t)NB * CH * HW * 2;   // 25165824 B (bf16)
    unsigned short* Qh  = (unsigned short*)(ws + 890880);
    unsigned short* Ql  = (unsigned short*)(ws + 890880 + PLANE_BYTES);
    unsigned short* Kh  = (unsigned short*)(ws + 890880 + 2 * PLANE_BYTES);
    unsigned short* Kl  = (unsigned short*)(ws + 890880 + 3 * PLANE_BYTES);
    unsigned short* Vc  = (unsigned short*)(ws + 890880 + 4 * PLANE_BYTES);
    unsigned short* Vct = (unsigned short*)(ws + 890880 + 5 * PLANE_BYTES);
    const size_t need_new = 890880 + 6 * PLANE_BYTES;      // ~76.4 MB

    if (ws_size >= need_new) {
        hipMemsetAsync(Sg, 0, 147456, stream);
        k_conv3<<<2304, 256, 0, stream>>>(q_fea, k_fea, v_fea, wq, wk, wv,
                                          Qh, Ql, Kh, Kl, Vc, ssqg);
        k_gram2<<<dim3(32, 16), 256, 0, stream>>>(Qh, Ql, Kh, Kl, Sg);
        k_attn<<<192, 256, 0, stream>>>(Sg, ssqg, temp, aw, Mg);
        k_w2<<<1152, 256, 0, stream>>>(wproj, Mg, W2);
        k_trans<<<dim3(256, 6, 2), 256, 0, stream>>>(Vc, Vct);
        k_gemm2<<<dim3(128, 3, 2), 256, 0, stream>>>(W2, Vct, out);
    } else {
        // old fallback path
        unsigned short* VcO = (unsigned short*)(ws + 890880);
        const size_t need_old = 890880 + PLANE_BYTES;
        const int staged = (ws_size >= need_old) ? 1 : 0;
        hipMemsetAsync(d_ws, 0, 153600, stream);
        k_gram<<<dim3(32, 8, 2), 256, 0, stream>>>(q_fea, k_fea, wq, wk, Sg, ssqg);
        k_attn<<<192, 256, 0, stream>>>(Sg, ssqg, temp, aw, Mg);
        k_w2<<<1152, 256, 0, stream>>>(wproj, Mg, W2);
        if (staged) k_vconv<<<768, 256, 0, stream>>>(v_fea, wv, VcO);
        k_gemm<<<dim3(128, 3, 2), 256, 0, stream>>>(W2, VcO, v_fea, wv, out, staged);
    }
}

// Round 5
// 320.450 us; speedup vs baseline: 2.6225x; 2.6225x over previous
//
#include <hip/hip_runtime.h>
#include <stdint.h>

#define NB 2
#define CH 384
#define NH 8
#define CPH 48
#define IMG 128
#define HW 16384

typedef float f32x4 __attribute__((ext_vector_type(4)));
typedef short bf16x8 __attribute__((ext_vector_type(8)));
typedef short short4v __attribute__((ext_vector_type(4)));

__device__ inline unsigned short f2bf(float f){
    unsigned u = __builtin_bit_cast(unsigned, f);
    u += 0x7FFFu + ((u >> 16) & 1u);
    return (unsigned short)(u >> 16);
}
__device__ inline float bf2f(unsigned short h){
    unsigned u = ((unsigned)h) << 16;
    return __builtin_bit_cast(float, u);
}

// ---------------------------------------------------------------------------
// k_conv3 (coalesced): one block per (tensor, b, ch) plane. dwconv3x3.
// Wave layout: lane = (rowpair rb=lane>>5, cx=lane&31). Each pass: 2 full rows.
// Loads: 32 lanes x float4 contiguous per row (full 128B lines); boundary rows
// are CLAMPED in-bounds and zeroed by multiplier (no OOB address ever formed).
// Halo via __shfl(lane +/- 1). Stores: 512B contiguous per instruction.
// ---------------------------------------------------------------------------
__global__ __launch_bounds__(256) void k_conv3(
    const float* __restrict__ qf, const float* __restrict__ kf,
    const float* __restrict__ vf,
    const float* __restrict__ wq, const float* __restrict__ wk,
    const float* __restrict__ wv,
    unsigned short* __restrict__ Qh, unsigned short* __restrict__ Ql,
    unsigned short* __restrict__ Kh, unsigned short* __restrict__ Kl,
    unsigned short* __restrict__ Vc, float* __restrict__ ssqg)
{
    const int p = blockIdx.x;            // 0..2303
    const int tensor = p / 768;          // 0=q,1=k,2=v
    const int bc = p % 768;              // b*384+ch
    const int ch = bc % CH, b = bc / CH;

    const float* plane; const float* wp9;
    unsigned short *oh, *ol;
    if (tensor == 0) { plane = qf + (size_t)bc * HW; wp9 = wq + ch * 9;
                       oh = Qh + (size_t)bc * HW; ol = Ql + (size_t)bc * HW; }
    else if (tensor == 1) { plane = kf + (size_t)bc * HW; wp9 = wk + ch * 9;
                       oh = Kh + (size_t)bc * HW; ol = Kl + (size_t)bc * HW; }
    else             { plane = vf + (size_t)bc * HW; wp9 = wv + ch * 9;
                       oh = Vc + (size_t)bc * HW; ol = nullptr; }

    float w9[9];
#pragma unroll
    for (int i = 0; i < 9; ++i) w9[i] = wp9[i];

    const int t = threadIdx.x;
    const int wvid = t >> 6, lane = t & 63;
    const int rb = lane >> 5, cx = lane & 31;

    float ssqacc = 0.f;

    for (int pass = 0; pass < 16; ++pass) {
        const int y = wvid * 32 + pass * 2 + rb;
        float o0 = 0.f, o1 = 0.f, o2 = 0.f, o3 = 0.f;
#pragma unroll
        for (int dy = 0; dy < 3; ++dy) {
            const int yy = y + dy - 1;
            const float vm = (yy >= 0 && yy < IMG) ? 1.f : 0.f;
            const int yc = yy < 0 ? 0 : (yy > IMG - 1 ? IMG - 1 : yy);
            float4 r4 = *(const float4*)(plane + yc * IMG + 4 * cx);
            r4.x *= vm; r4.y *= vm; r4.z *= vm; r4.w *= vm;
            float lf = __shfl(r4.w, (lane + 63) & 63);
            if (cx == 0) lf = 0.f;
            float rt = __shfl(r4.x, (lane + 1) & 63);
            if (cx == 31) rt = 0.f;
            const float a0 = w9[dy * 3], a1 = w9[dy * 3 + 1], a2 = w9[dy * 3 + 2];
            o0 += a0 * lf   + a1 * r4.x + a2 * r4.y;
            o1 += a0 * r4.x + a1 * r4.y + a2 * r4.z;
            o2 += a0 * r4.y + a1 * r4.z + a2 * r4.w;
            o3 += a0 * r4.z + a1 * r4.w + a2 * rt;
        }
        const int xb = 4 * cx;
        if (tensor < 2) {
            ssqacc += o0 * o0 + o1 * o1 + o2 * o2 + o3 * o3;
            unsigned short h0 = f2bf(o0), h1 = f2bf(o1), h2 = f2bf(o2), h3 = f2bf(o3);
            short4v hv = {(short)h0, (short)h1, (short)h2, (short)h3};
            short4v lv = {(short)f2bf(o0 - bf2f(h0)), (short)f2bf(o1 - bf2f(h1)),
                          (short)f2bf(o2 - bf2f(h2)), (short)f2bf(o3 - bf2f(h3))};
            *(short4v*)(oh + y * IMG + xb) = hv;
            *(short4v*)(ol + y * IMG + xb) = lv;
        } else {
            short4v pv = {(short)f2bf(o0), (short)f2bf(o1), (short)f2bf(o2), (short)f2bf(o3)};
            *(short4v*)(oh + y * IMG + xb) = pv;
        }
    }

    if (tensor < 2) {
#pragma unroll
        for (int off = 32; off; off >>= 1) ssqacc += __shfl_xor(ssqacc, off);
        __shared__ float ssr[4];
        if (lane == 0) ssr[wvid] = ssqacc;
        __syncthreads();
        if (t == 0) {
            int h = ch / CPH, c = ch % CPH;
            ssqg[(b * NH + h) * 96 + tensor * 48 + c] = ssr[0] + ssr[1] + ssr[2] + ssr[3];
        }
    }
}

// ---------------------------------------------------------------------------
// k_gram2: S[bh] = qh*(kh)^T + qh*(kl)^T + ql*(kh)^T over K=16384 (split)
// ---------------------------------------------------------------------------
__global__ __launch_bounds__(256) void k_gram2(
    const unsigned short* __restrict__ Qh, const unsigned short* __restrict__ Ql,
    const unsigned short* __restrict__ Kh, const unsigned short* __restrict__ Kl,
    float* __restrict__ Sg)
{
    __shared__ float sred[4][2304];
    const int t = threadIdx.x;
    const int s = blockIdx.x, bh = blockIdx.y;
    const int wid = t >> 6, lane = t & 63, quad = lane >> 4, l15 = lane & 15;
    const size_t pbase = (size_t)((bh >> 3) * CH + (bh & 7) * CPH) * HW;

    f32x4 acc[3][3];
#pragma unroll
    for (int i = 0; i < 3; ++i)
#pragma unroll
        for (int j = 0; j < 3; ++j) acc[i][j] = (f32x4){0.f, 0.f, 0.f, 0.f};

    const int k0 = s * 512 + wid * 128;
#pragma unroll
    for (int ks = 0; ks < 4; ++ks) {
        const int px = k0 + ks * 32 + quad * 8;
        bf16x8 qh[3], ql_[3], kh[3], kl[3];
#pragma unroll
        for (int i = 0; i < 3; ++i) {
            size_t off = pbase + (size_t)(i * 16 + l15) * HW + px;
            qh[i]  = *(const bf16x8*)(Qh + off);
            ql_[i] = *(const bf16x8*)(Ql + off);
            kh[i]  = *(const bf16x8*)(Kh + off);
            kl[i]  = *(const bf16x8*)(Kl + off);
        }
#pragma unroll
        for (int ci = 0; ci < 3; ++ci)
#pragma unroll
            for (int di = 0; di < 3; ++di) {
                acc[ci][di] = __builtin_amdgcn_mfma_f32_16x16x32_bf16(qh[ci],  kh[di], acc[ci][di], 0, 0, 0);
                acc[ci][di] = __builtin_amdgcn_mfma_f32_16x16x32_bf16(qh[ci],  kl[di], acc[ci][di], 0, 0, 0);
                acc[ci][di] = __builtin_amdgcn_mfma_f32_16x16x32_bf16(ql_[ci], kh[di], acc[ci][di], 0, 0, 0);
            }
    }
#pragma unroll
    for (int ci = 0; ci < 3; ++ci)
#pragma unroll
        for (int di = 0; di < 3; ++di)
#pragma unroll
            for (int r = 0; r < 4; ++r)
                sred[wid][(ci * 16 + quad * 4 + r) * 48 + di * 16 + l15] = acc[ci][di][r];
    __syncthreads();
    float* Sbh = Sg + (size_t)bh * 2304;
#pragma unroll
    for (int i = 0; i < 9; ++i) {
        int e = t * 9 + i;
        atomicAdd(&Sbh[e], sred[0][e] + sred[1][e] + sred[2][e] + sred[3][e]);
    }
}

// ---------------------------------------------------------------------------
// k_attn: per attn row: normalize, rank, 4 nested-topk softmaxes -> M
// ---------------------------------------------------------------------------
__global__ void k_attn(const float* __restrict__ Sg, const float* __restrict__ ssqg,
                       const float* __restrict__ temp, const float* __restrict__ aw,
                       float* __restrict__ Mg)
{
    const int t = threadIdx.x;
    const int r = blockIdx.x * 4 + (t >> 6);
    const int lane = t & 63;
    const int c = r % 48, h = (r / 48) % NH, b = r / (48 * NH);
    const float* Srow = Sg + ((size_t)(b * NH + h) * 48 + c) * 48;
    const float* sq = ssqg + (size_t)(b * NH + h) * 96;

    float v = -3.0e38f;
    if (lane < 48) {
        float nq = fmaxf(sqrtf(sq[c]), 1e-12f);
        float nk = fmaxf(sqrtf(sq[48 + lane]), 1e-12f);
        v = Srow[lane] / (nq * nk) * temp[h];
    }
    float m = v;
#pragma unroll
    for (int off = 32; off; off >>= 1) m = fmaxf(m, __shfl_xor(m, off));
    int rank = 0;
    for (int e = 0; e < 48; ++e) {
        float ve = __shfl(v, e);
        rank += ((ve > v) || (ve == v && e < lane)) ? 1 : 0;
    }
    float ed = (lane < 48) ? __expf(v - m) : 0.f;
    const int K4[4] = {24, 32, 36, 38};
    float f = 0.f;
#pragma unroll
    for (int i = 0; i < 4; ++i) {
        float x = (rank < K4[i]) ? ed : 0.f;
#pragma unroll
        for (int off = 32; off; off >>= 1) x += __shfl_xor(x, off);
        if (rank < K4[i]) f += aw[i] / x;
    }
    if (lane < 48) Mg[((size_t)(b * NH + h) * 48 + c) * 48 + lane] = ed * f;
}

// ---------------------------------------------------------------------------
// k_w2: W2[b][co][gd] = sum_c Wproj[co][h*48+c] * M[b,h][c][d]  -> bf16
// ---------------------------------------------------------------------------
__global__ void k_w2(const float* __restrict__ wproj, const float* __restrict__ Mg,
                     unsigned short* __restrict__ W2)
{
    int idx = blockIdx.x * 256 + threadIdx.x;
    int gd = idx % 384; int co = (idx / 384) % 384; int b = idx / (384 * 384);
    int h = gd / 48, d = gd % 48;
    const float* wp = wproj + (size_t)co * 384 + h * 48;
    const float* Mp = Mg + (size_t)(b * NH + h) * 2304 + d;
    float s = 0.f;
#pragma unroll
    for (int cc = 0; cc < 48; ++cc) s += wp[cc] * Mp[cc * 48];
    W2[idx] = f2bf(s);
}

// ---------------------------------------------------------------------------
// k_trans: Vc[b][ch][n] -> Vct[b][n][ch]  (64x64 LDS tiles)
// ---------------------------------------------------------------------------
__global__ __launch_bounds__(256) void k_trans(const unsigned short* __restrict__ Vc,
                                               unsigned short* __restrict__ Vct)
{
    __shared__ unsigned short S[64][66];
    const int nt = blockIdx.x, ct = blockIdx.y, b = blockIdx.z;
    const int t = threadIdx.x, r = t >> 2, seg = t & 3;
    const unsigned short* src = Vc + (size_t)(b * CH + ct * 64 + r) * HW + nt * 64 + seg * 16;
    *(bf16x8*)&S[r][seg * 16]     = *(const bf16x8*)src;
    *(bf16x8*)&S[r][seg * 16 + 8] = *(const bf16x8*)(src + 8);
    __syncthreads();
    unsigned short tmp[16];
#pragma unroll
    for (int i = 0; i < 16; ++i) tmp[i] = S[seg * 16 + i][r];
    unsigned short* dst = Vct + ((size_t)b * HW + nt * 64 + r) * CH + ct * 64 + seg * 16;
    *(bf16x8*)dst       = *(const bf16x8*)&tmp[0];
    *(bf16x8*)(dst + 8) = *(const bf16x8*)&tmp[8];
}

// ---------------------------------------------------------------------------
// k_gemm2: out[b] = W2[b] (384x384) @ Vct (LDS-free MFMA GEMM)
// ---------------------------------------------------------------------------
__global__ __launch_bounds__(256) void k_gemm2(const unsigned short* __restrict__ W2,
        const unsigned short* __restrict__ Vct, float* __restrict__ out)
{
    const int t = threadIdx.x;
    const int y = blockIdx.x, mt = blockIdx.y, b = blockIdx.z;
    const int wid = t >> 6, lane = t & 63, quad = lane >> 4, l15 = lane & 15;
    const int wm = wid >> 1, wn = wid & 1;

    f32x4 acc[4][4];
#pragma unroll
    for (int i = 0; i < 4; ++i)
#pragma unroll
        for (int j = 0; j < 4; ++j) acc[i][j] = (f32x4){0.f, 0.f, 0.f, 0.f};

    const unsigned short* Ab[4];
    const unsigned short* Bb[4];
#pragma unroll
    for (int i = 0; i < 4; ++i) {
        Ab[i] = W2 + (size_t)(b * CH + mt * 128 + wm * 64 + i * 16 + l15) * CH + quad * 8;
        Bb[i] = Vct + ((size_t)b * HW + y * IMG + wn * 64 + i * 16 + l15) * CH + quad * 8;
    }

    for (int kt = 0; kt < 12; ++kt) {
        const int K0 = kt * 32;
        bf16x8 af[4], bfr[4];
#pragma unroll
        for (int i = 0; i < 4; ++i) af[i]  = *(const bf16x8*)(Ab[i] + K0);
#pragma unroll
        for (int i = 0; i < 4; ++i) bfr[i] = *(const bf16x8*)(Bb[i] + K0);
#pragma unroll
        for (int mi = 0; mi < 4; ++mi)
#pragma unroll
            for (int ni = 0; ni < 4; ++ni)
                acc[mi][ni] = __builtin_amdgcn_mfma_f32_16x16x32_bf16(af[mi], bfr[ni], acc[mi][ni], 0, 0, 0);
    }
#pragma unroll
    for (int mi = 0; mi < 4; ++mi)
#pragma unroll
        for (int ni = 0; ni < 4; ++ni)
#pragma unroll
            for (int r = 0; r < 4; ++r) {
                int co = mt * 128 + wm * 64 + mi * 16 + quad * 4 + r;
                int n  = y * IMG + wn * 64 + ni * 16 + l15;
                out[(size_t)(b * CH + co) * HW + n] = acc[mi][ni][r];
            }
}

// ---------------------------------------------------------------------------
extern "C" void kernel_launch(void* const* d_in, const int* in_sizes, int n_in,
                              void* d_out, int out_size, void* d_ws, size_t ws_size,
                              hipStream_t stream)
{
    const float* k_fea = (const float*)d_in[0];
    const float* v_fea = (const float*)d_in[1];
    const float* q_fea = (const float*)d_in[2];
    const float* wq = (const float*)d_in[3];
    const float* wk = (const float*)d_in[4];
    const float* wv = (const float*)d_in[5];
    const float* wproj = (const float*)d_in[6];
    const float* temp = (const float*)d_in[7];
    const float* aw = (const float*)d_in[8];
    float* out = (float*)d_out;

    char* ws = (char*)d_ws;
    float* Sg   = (float*)ws;                              // 147456 B
    float* ssqg = (float*)(ws + 147456);                   // 6144 B
    float* Mg   = (float*)(ws + 153600);                   // 147456 B
    unsigned short* W2 = (unsigned short*)(ws + 301056);   // 589824 B

    const size_t PLANE_BYTES = (size_t)NB * CH * HW * 2;   // 25165824 B
    unsigned short* Qh  = (unsigned short*)(ws + 890880);
    unsigned short* Ql  = (unsigned short*)(ws + 890880 + PLANE_BYTES);
    unsigned short* Kh  = (unsigned short*)(ws + 890880 + 2 * PLANE_BYTES);
    unsigned short* Kl  = (unsigned short*)(ws + 890880 + 3 * PLANE_BYTES);
    unsigned short* Vc  = (unsigned short*)(ws + 890880 + 4 * PLANE_BYTES);
    unsigned short* Vct = (unsigned short*)(ws + 890880 + 5 * PLANE_BYTES);

    hipMemsetAsync(Sg, 0, 147456, stream);
    k_conv3<<<2304, 256, 0, stream>>>(q_fea, k_fea, v_fea, wq, wk, wv,
                                      Qh, Ql, Kh, Kl, Vc, ssqg);
    k_gram2<<<dim3(32, 16), 256, 0, stream>>>(Qh, Ql, Kh, Kl, Sg);
    k_attn<<<192, 256, 0, stream>>>(Sg, ssqg, temp, aw, Mg);
    k_w2<<<1152, 256, 0, stream>>>(wproj, Mg, W2);
    k_trans<<<dim3(256, 6, 2), 256, 0, stream>>>(Vc, Vct);
    k_gemm2<<<dim3(128, 3, 2), 256, 0, stream>>>(W2, Vct, out);
}